// Round 1
// baseline (727.704 us; speedup 1.0000x reference)
//
#include <hip/hip_runtime.h>
#include <math.h>

#define B 32
#define NF 128
#define DE 256
#define DH 512
#define G 2
#define SL 8

// ---------------------------------------------------------------------------
// K1: query[b,d] = dot(c_i[b,:], map_c_w[d,:]) + map_c_b[d]
// One wave per output (8192 waves). 512 = 64 lanes x 8 floats (2x float4).
// ---------------------------------------------------------------------------
__global__ __launch_bounds__(256) void k_query(const float* __restrict__ c_i,
                                               const float* __restrict__ w,
                                               const float* __restrict__ bias,
                                               float* __restrict__ query) {
    const int wave = blockIdx.x * 4 + (threadIdx.x >> 6);
    const int lane = threadIdx.x & 63;
    const int b = wave >> 8;   // 256 outputs (d) per batch
    const int d = wave & 255;
    const float4* cv = (const float4*)(c_i + (size_t)b * DH);
    const float4* wv = (const float4*)(w + (size_t)d * DH);
    float4 a0 = cv[lane];
    float4 b0 = wv[lane];
    float4 a1 = cv[64 + lane];
    float4 b1 = wv[64 + lane];
    float acc = a0.x * b0.x + a0.y * b0.y + a0.z * b0.z + a0.w * b0.w
              + a1.x * b1.x + a1.y * b1.y + a1.z * b1.z + a1.w * b1.w;
    #pragma unroll
    for (int m = 32; m; m >>= 1) acc += __shfl_xor(acc, m, 64);
    if (lane == 0) query[wave] = acc + bias[d];
}

// ---------------------------------------------------------------------------
// K2: weit[b,n,m] = sigmoid(dot(feat_edge[b,n,m,:], query[b,:]))
// One wave per element-chunk of 32 consecutive (b,n,m). d=256 = 64 lanes x
// float4 -> one coalesced 1024B wave-load per element. Memory-bound kernel.
// ---------------------------------------------------------------------------
__global__ __launch_bounds__(256) void k_weit(const float* __restrict__ fe,
                                              const float* __restrict__ query,
                                              float* __restrict__ weit) {
    const int lane = threadIdx.x & 63;
    const int wave = blockIdx.x * 4 + (threadIdx.x >> 6);
    const int e0 = wave * 32;          // 524288 elements total, chunks of 32
    const int b = e0 >> 14;            // 16384 elements per batch
    const float4 q = ((const float4*)(query + (size_t)b * DE))[lane];
    const float4* fv = (const float4*)(fe + (size_t)e0 * DE);
    #pragma unroll 4
    for (int c = 0; c < 32; ++c) {
        float4 f = fv[(size_t)c * 64 + lane];
        float acc = f.x * q.x + f.y * q.y + f.z * q.z + f.w * q.w;
        #pragma unroll
        for (int m = 32; m; m >>= 1) acc += __shfl_xor(acc, m, 64);
        if (lane == 0) weit[e0 + c] = 1.0f / (1.0f + __expf(-acc));
    }
}

// ---------------------------------------------------------------------------
// K3: P = M @ M (per batch). Block = 16 rows of one batch; full M in LDS.
// grid = 32 batches * 8 row-blocks = 256 blocks.
// ---------------------------------------------------------------------------
__global__ __launch_bounds__(256) void k_msq(const float* __restrict__ rm,
                                             float* __restrict__ P) {
    __shared__ float Ms[NF * NF];          // 64 KiB
    const int b  = blockIdx.x >> 3;
    const int i0 = (blockIdx.x & 7) * 16;
    const int t  = threadIdx.x;
    const float4* src = (const float4*)(rm + (size_t)b * NF * NF);
    float4* dst = (float4*)Ms;
    for (int idx = t; idx < NF * NF / 4; idx += 256) dst[idx] = src[idx];
    __syncthreads();
    const int j  = t & 127;
    const int ig = t >> 7;                 // 0 or 1
    const int ibase = i0 + ig * 8;         // 8 rows per thread
    float acc[8] = {0, 0, 0, 0, 0, 0, 0, 0};
    for (int k = 0; k < NF; k += 4) {
        const float b0 = Ms[(k + 0) * NF + j];
        const float b1 = Ms[(k + 1) * NF + j];
        const float b2 = Ms[(k + 2) * NF + j];
        const float b3 = Ms[(k + 3) * NF + j];
        #pragma unroll
        for (int r = 0; r < 8; ++r) {
            const float4 a = *(const float4*)(Ms + (ibase + r) * NF + k);
            acc[r] += a.x * b0 + a.y * b1 + a.z * b2 + a.w * b3;
        }
    }
    float* Pb = P + (size_t)b * NF * NF;
    #pragma unroll
    for (int r = 0; r < 8; ++r) Pb[(ibase + r) * NF + j] = acc[r];
}

// ---------------------------------------------------------------------------
// K4: F = M + 0.9*P + P @ (0.81*M + 0.729*P)        (P = M^2)
//   = M + 0.9M^2 + 0.81M^3 + 0.729M^4
// C = 0.81M + 0.729P staged in LDS (64 KiB); A-side rows of P read from
// global (wave-broadcast, L1/L2-resident). grid = 256 blocks.
// ---------------------------------------------------------------------------
__global__ __launch_bounds__(256) void k_final(const float* __restrict__ rm,
                                               const float* __restrict__ P,
                                               float* __restrict__ F) {
    __shared__ float Cs[NF * NF];          // 64 KiB
    const int b  = blockIdx.x >> 3;
    const int i0 = (blockIdx.x & 7) * 16;
    const int t  = threadIdx.x;
    const float* Mb = rm + (size_t)b * NF * NF;
    const float* Pb = P + (size_t)b * NF * NF;
    const float4* mv = (const float4*)Mb;
    const float4* pv = (const float4*)Pb;
    float4* cs4 = (float4*)Cs;
    for (int idx = t; idx < NF * NF / 4; idx += 256) {
        float4 m4 = mv[idx], p4 = pv[idx], c;
        c.x = 0.81f * m4.x + 0.729f * p4.x;
        c.y = 0.81f * m4.y + 0.729f * p4.y;
        c.z = 0.81f * m4.z + 0.729f * p4.z;
        c.w = 0.81f * m4.w + 0.729f * p4.w;
        cs4[idx] = c;
    }
    __syncthreads();
    const int j  = t & 127;
    const int ig = t >> 7;
    const int ibase = i0 + ig * 8;
    float acc[8] = {0, 0, 0, 0, 0, 0, 0, 0};
    for (int k = 0; k < NF; k += 4) {
        const float b0 = Cs[(k + 0) * NF + j];
        const float b1 = Cs[(k + 1) * NF + j];
        const float b2 = Cs[(k + 2) * NF + j];
        const float b3 = Cs[(k + 3) * NF + j];
        #pragma unroll
        for (int r = 0; r < 8; ++r) {
            const float4 a = *(const float4*)(Pb + (size_t)(ibase + r) * NF + k);
            acc[r] += a.x * b0 + a.y * b1 + a.z * b2 + a.w * b3;
        }
    }
    float* Fb = F + (size_t)b * NF * NF;
    #pragma unroll
    for (int r = 0; r < 8; ++r) {
        const int i = ibase + r;
        Fb[i * NF + j] = Mb[i * NF + j] + 0.9f * Pb[i * NF + j] + acc[r];
    }
}

// ---------------------------------------------------------------------------
// K5: att_in = einsum(att_stack, stack_ptr); att_out = einsum(att_in, W*F);
// norm by m-max; blend into att_stack_new; write all 4 outputs.
// One block per batch. thread t -> (m = t&127, g = t>>7).
// ---------------------------------------------------------------------------
__global__ __launch_bounds__(256) void k_out(const float* __restrict__ att_stack,
                                             const float* __restrict__ stack_ptr,
                                             const float* __restrict__ W,
                                             const float* __restrict__ F,
                                             float* __restrict__ out) {
    __shared__ float sps[SL];
    __shared__ float att_in[G * NF];
    __shared__ float redmax[4];
    const int b = blockIdx.x;
    const int t = threadIdx.x;
    if (t < SL) sps[t] = stack_ptr[b * SL + t];
    __syncthreads();
    {   // att_in[b,n,g] = sum_s att_stack[b,n,g,s] * sp[s]
        const int n = t >> 1, g = t & 1;
        const float* as = att_stack + ((size_t)(b * NF + n) * G + g) * SL;
        float v = 0.0f;
        #pragma unroll
        for (int s = 0; s < SL; ++s) v += as[s] * sps[s];
        att_in[g * NF + n] = v;
    }
    __syncthreads();
    const int m = t & 127, g = t >> 7;
    const float* Wb = W + (size_t)b * NF * NF;
    const float* Fb = F + (size_t)b * NF * NF;
    const float* ai = att_in + g * NF;
    float acc = 0.0f;
    for (int n = 0; n < NF; ++n)
        acc += ai[n] * Wb[n * NF + m] * Fb[n * NF + m];
    // norm = max over m per (b,g); clamp to >= 1
    float wm = acc;
    #pragma unroll
    for (int mm = 32; mm; mm >>= 1) wm = fmaxf(wm, __shfl_xor(wm, mm, 64));
    if ((t & 63) == 0) redmax[t >> 6] = wm;   // waves 0,1 -> g=0; 2,3 -> g=1
    __syncthreads();
    float norm = fmaxf(redmax[g * 2], redmax[g * 2 + 1]);
    norm = (norm <= 1.0f) ? 1.0f : norm;
    const float v = acc / norm;
    // output 0: att_stack_new[b,m,g,s]
    const size_t base = ((size_t)(b * NF + m) * G + g) * SL;
    #pragma unroll
    for (int s = 0; s < SL; ++s)
        out[base + s] = v * sps[s] + att_stack[base + s] * (1.0f - sps[s]);
    // output 1: stack_ptr passthrough
    if (t < SL) out[(size_t)B * NF * G * SL + b * SL + t] = sps[t];
    // outputs 2+3: zeros (2 * B * DH floats)
    const size_t zbase = (size_t)B * NF * G * SL + B * SL;
    for (int idx = t; idx < 2 * DH; idx += 256)
        out[zbase + (size_t)b * 2 * DH + idx] = 0.0f;
}

// ---------------------------------------------------------------------------
extern "C" void kernel_launch(void* const* d_in, const int* in_sizes, int n_in,
                              void* d_out, int out_size, void* d_ws, size_t ws_size,
                              hipStream_t stream) {
    const float* fe        = (const float*)d_in[2];   // feat_edge
    const float* c_i       = (const float*)d_in[3];
    const float* rm        = (const float*)d_in[4];   // relation_mask
    const float* att_stack = (const float*)d_in[5];
    const float* sp        = (const float*)d_in[6];   // stack_ptr
    const float* mcw       = (const float*)d_in[8];   // map_c_w
    const float* mcb       = (const float*)d_in[9];   // map_c_b
    float* out = (float*)d_out;

    float* ws    = (float*)d_ws;
    float* query = ws;                     // 32*256        = 8192
    float* weit  = query + 8192;           // 32*128*128    = 524288
    float* P     = weit + 524288;          // 524288
    float* F     = P + 524288;             // 524288  (total ~6.2 MiB)

    hipLaunchKernelGGL(k_query, dim3(2048), dim3(256), 0, stream, c_i, mcw, mcb, query);
    hipLaunchKernelGGL(k_msq,   dim3(256),  dim3(256), 0, stream, rm, P);
    hipLaunchKernelGGL(k_final, dim3(256),  dim3(256), 0, stream, rm, P, F);
    hipLaunchKernelGGL(k_weit,  dim3(4096), dim3(256), 0, stream, fe, query, weit);
    hipLaunchKernelGGL(k_out,   dim3(32),   dim3(256), 0, stream, att_stack, sp, weit, F, out);
}